// Round 3
// baseline (267.802 us; speedup 1.0000x reference)
//
#include <hip/hip_runtime.h>
#include <hip/hip_bf16.h>

#define N_NODES 100000
#define N_EDGES 262144
#define IN_DIM 768
#define HIDDEN 256
#define BM 256
#define BN 256
#define BK 64
#define NK (IN_DIM / BK)      // 12
#define M_BLOCKS 391          // ceil(100000/256)
#define M_PAD (M_BLOCKS * BM) // 100096
#define WT_TILE_BYTES (BN * BK * 2) // 32768

typedef __attribute__((ext_vector_type(8))) short short8;
typedef __attribute__((ext_vector_type(4))) float f32x4;

__device__ __forceinline__ unsigned short f32_to_bf16(float f) {
    unsigned int u = __builtin_bit_cast(unsigned int, f);
    u = (u + 0x7FFFu + ((u >> 16) & 1u)) >> 16;
    return (unsigned short)u;
}
__device__ __forceinline__ float bf16_to_f32(unsigned short h) {
    unsigned int u = ((unsigned int)h) << 16;
    return __builtin_bit_cast(float, u);
}
__device__ __forceinline__ void gload_lds16(const void* gsrc, void* lds) {
    __builtin_amdgcn_global_load_lds(
        (const __attribute__((address_space(1))) unsigned int*)gsrc,
        (__attribute__((address_space(3))) unsigned int*)lds,
        16, 0, 0);
}

// WtT[g][ks][n][c][j] = bf16(W1[g*768 + ks*64 + (c^(n&7))*8 + j][n])
// i.e. the INVERSE-swizzled image, so linear global_load_lds writes produce
// the swizzled LDS tile that compute() reads with byte ^= ((n&7)<<4).
__global__ __launch_bounds__(256) void convert_w1(const float* __restrict__ W1,
                                                  unsigned short* __restrict__ WtT) {
    int t = blockIdx.x * blockDim.x + threadIdx.x;
    if (t >= 2 * NK * BN * BK) return;
    int g  = t / (NK * BN * BK);
    int r  = t % (NK * BN * BK);
    int ks = r / (BN * BK);
    int r2 = r % (BN * BK);
    int n  = r2 / BK;
    int w  = r2 % BK;
    int c  = w >> 3;
    int j  = w & 7;
    int k  = ks * BK + ((c ^ (n & 7)) << 3) + j;
    WtT[t] = f32_to_bf16(W1[(size_t)(g * IN_DIM + k) * HIDDEN + n]);
}

// P = bf16(X) @ bf16(W1half), one 256x256 tile per block, K=768.
// Double-buffered LDS, one barrier per K-step. B: global_load_lds from
// pre-swizzled WtT. A: reg-staged f32->bf16 with XOR-swizzled ds_write.
__global__ __launch_bounds__(512, 2) void node_gemm(const float* __restrict__ X0,
                                                    const float* __restrict__ X1,
                                                    const unsigned short* __restrict__ WtT,
                                                    unsigned short* __restrict__ Pout,
                                                    unsigned short* __restrict__ Qout) {
    const int g = blockIdx.y;
    const float* __restrict__ X = g ? X1 : X0;
    unsigned short* __restrict__ Out = g ? Qout : Pout;
    const char* wt_base = (const char*)WtT + (size_t)g * NK * WT_TILE_BYTES;

    __shared__ unsigned short As[2][BM * BK]; // 2 x 32KB, swizzled rows (128B)
    __shared__ unsigned short Bs[2][BN * BK]; // 2 x 32KB, swizzled rows (128B)

    const int m0   = blockIdx.x * BM;
    const int tid  = threadIdx.x;
    const int lane = tid & 63;
    const int wid  = tid >> 6;
    const int wm   = wid >> 2; // 0..1 -> 128-row slab
    const int wn   = wid & 3;  // 0..3 -> 64-col slab

    const int ar = tid >> 4;   // 0..31, row step +32 per pass
    const int ap = tid & 15;   // float4 index within row

    float4 areg[8];
    f32x4 acc[8][4] = {};

    auto load_a = [&](int ks) {
        const int k0 = ks * BK;
#pragma unroll
        for (int p = 0; p < 8; ++p) {
            int r = ar + p * 32;
            int rg = m0 + r;
            if (rg >= N_NODES) rg = N_NODES - 1; // pad rows get copies
            areg[p] = *(const float4*)(X + (size_t)rg * IN_DIM + k0 + ap * 4);
        }
    };
    auto write_a = [&](int buf) {
        char* base = (char*)As[buf];
#pragma unroll
        for (int p = 0; p < 8; ++p) {
            int r = ar + p * 32;
            float4 v = areg[p];
            ushort4 w;
            w.x = f32_to_bf16(v.x); w.y = f32_to_bf16(v.y);
            w.z = f32_to_bf16(v.z); w.w = f32_to_bf16(v.w);
            *(ushort4*)(base + r * 128 + ((ap * 8) ^ ((r & 7) << 4))) = w;
        }
    };
    auto load_b = [&](int ks, int buf) {
        const char* gsrc = wt_base + (size_t)ks * WT_TILE_BYTES + wid * 4096 + lane * 16;
        char* lbase = (char*)Bs[buf] + wid * 4096; // wave-uniform; HW adds lane*16
#pragma unroll
        for (int j = 0; j < 4; ++j)
            gload_lds16(gsrc + j * 1024, lbase + j * 1024);
    };
    auto compute = [&](int buf) {
        const char* a_base = (const char*)As[buf];
        const char* b_base = (const char*)Bs[buf];
#pragma unroll
        for (int kk = 0; kk < 2; ++kk) {
            const int kb = kk * 64 + ((lane >> 4) << 4);
            short8 bfr[4];
#pragma unroll
            for (int ni = 0; ni < 4; ++ni) {
                int n = wn * 64 + ni * 16 + (lane & 15);
                bfr[ni] = *(const short8*)(b_base + n * 128 + (kb ^ ((n & 7) << 4)));
            }
            __builtin_amdgcn_s_setprio(1);
#pragma unroll
            for (int mi = 0; mi < 8; ++mi) {
                int r = wm * 128 + mi * 16 + (lane & 15);
                short8 a = *(const short8*)(a_base + r * 128 + (kb ^ ((r & 7) << 4)));
#pragma unroll
                for (int ni = 0; ni < 4; ++ni)
                    // swapped operands: D[n][m] -> lane holds 4 consecutive n-cols
                    acc[mi][ni] = __builtin_amdgcn_mfma_f32_16x16x32_bf16(
                        bfr[ni], a, acc[mi][ni], 0, 0, 0);
            }
            __builtin_amdgcn_s_setprio(0);
        }
    };

    // prologue: stage tile 0
    load_b(0, 0);
    load_a(0);
    write_a(0);
    __syncthreads();
    int cur = 0;
    for (int ks = 0; ks < NK; ++ks) {
        if (ks + 1 < NK) {
            load_b(ks + 1, cur ^ 1); // direct-to-LDS, drains at the barrier
            load_a(ks + 1);          // vmcnt slack = whole compute phase
        }
        compute(cur);
        if (ks + 1 < NK) write_a(cur ^ 1);
        __syncthreads();
        cur ^= 1;
    }

    // store: m = m0 + wm*128 + mi*16 + (lane&15), n = wn*64 + ni*16 + (lane>>4)*4 + reg
    const int mrow = wm * 128 + (lane & 15);
    const int nb0  = wn * 64 + ((lane >> 4) << 2);
#pragma unroll
    for (int mi = 0; mi < 8; ++mi) {
        size_t mg = (size_t)(m0 + mrow + mi * 16);
#pragma unroll
        for (int ni = 0; ni < 4; ++ni) {
            f32x4 a = acc[mi][ni];
            ushort4 w;
            w.x = f32_to_bf16(a[0]); w.y = f32_to_bf16(a[1]);
            w.z = f32_to_bf16(a[2]); w.w = f32_to_bf16(a[3]);
            *(ushort4*)(Out + mg * HIDDEN + nb0 + ni * 16) = w;
        }
    }
}

// out[e] = relu(P[s]+Q[d]+b1) . W2 + b2 ; one wave per edge, lane j owns dims 4j..4j+3
__global__ __launch_bounds__(256) void edge_mlp(const unsigned short* __restrict__ P,
                                                const unsigned short* __restrict__ Q,
                                                const int* __restrict__ s_idx,
                                                const int* __restrict__ d_idx,
                                                const float* __restrict__ b1,
                                                const float* __restrict__ W2,
                                                const float* __restrict__ b2,
                                                float* __restrict__ out) {
    const int lane = threadIdx.x & 63;
    const int gw = (blockIdx.x * blockDim.x + threadIdx.x) >> 6;
    const int nw = (gridDim.x * blockDim.x) >> 6;
    const float4 b1v = *(const float4*)(b1 + lane * 4);
    const float4 w2v = *(const float4*)(W2 + lane * 4);
    const float b2s = *b2;
    for (int e = gw; e < N_EDGES; e += nw) {
        int s = s_idx[e];
        int d = d_idx[e];
        ushort4 pv = *(const ushort4*)(P + (size_t)s * HIDDEN + lane * 4);
        ushort4 qv = *(const ushort4*)(Q + (size_t)d * HIDDEN + lane * 4);
        float h, sum;
        h = bf16_to_f32(pv.x) + bf16_to_f32(qv.x) + b1v.x; h = fmaxf(h, 0.f); sum  = h * w2v.x;
        h = bf16_to_f32(pv.y) + bf16_to_f32(qv.y) + b1v.y; h = fmaxf(h, 0.f); sum += h * w2v.y;
        h = bf16_to_f32(pv.z) + bf16_to_f32(qv.z) + b1v.z; h = fmaxf(h, 0.f); sum += h * w2v.z;
        h = bf16_to_f32(pv.w) + bf16_to_f32(qv.w) + b1v.w; h = fmaxf(h, 0.f); sum += h * w2v.w;
#pragma unroll
        for (int off = 32; off; off >>= 1) sum += __shfl_xor(sum, off, 64);
        if (lane == 0) out[e] = sum + b2s;
    }
}

extern "C" void kernel_launch(void* const* d_in, const int* in_sizes, int n_in,
                              void* d_out, int out_size, void* d_ws, size_t ws_size,
                              hipStream_t stream) {
    const float* x_src = (const float*)d_in[0];
    const float* x_dst = (const float*)d_in[1];
    const int*   s_idx = (const int*)d_in[2];
    const int*   d_idx = (const int*)d_in[3];
    const float* W1    = (const float*)d_in[4];
    const float* b1    = (const float*)d_in[5];
    const float* W2    = (const float*)d_in[6];
    const float* b2    = (const float*)d_in[7];
    float* out = (float*)d_out;

    char* ws = (char*)d_ws;
    // layout: WtT (786432 B) | P (M_PAD*256*2 B) | Q (M_PAD*256*2 B) => ~103.3 MB
    unsigned short* WtT = (unsigned short*)ws;
    unsigned short* P   = (unsigned short*)(ws + 786432);
    unsigned short* Q   = (unsigned short*)(ws + 786432 + (size_t)M_PAD * HIDDEN * 2);

    convert_w1<<<(2 * NK * BN * BK + 255) / 256, 256, 0, stream>>>(W1, WtT);

    dim3 gg(M_BLOCKS, 2);
    node_gemm<<<gg, 512, 0, stream>>>(x_src, x_dst, WtT, P, Q);

    edge_mlp<<<2048, 256, 0, stream>>>(P, Q, s_idx, d_idx, b1, W2, b2, out);
}

// Round 4
// 251.471 us; speedup vs baseline: 1.0649x; 1.0649x over previous
//
#include <hip/hip_runtime.h>
#include <hip/hip_bf16.h>

#define N_NODES 100000
#define N_EDGES 262144
#define IN_DIM 768
#define HIDDEN 256
#define BM 128
#define BN 256
#define BK 32
#define NK (IN_DIM / BK)      // 24
#define M_BLOCKS 782          // ceil(100000/128)
#define M_PAD (M_BLOCKS * BM) // 100096
#define WT_TILE_BYTES (BN * BK * 2) // 16384

typedef __attribute__((ext_vector_type(8))) short short8;
typedef __attribute__((ext_vector_type(4))) float f32x4;

#define WAITV(n) asm volatile("s_waitcnt vmcnt(" #n ")" ::: "memory")
#define FENCE()  asm volatile("" ::: "memory")

__device__ __forceinline__ unsigned short f32_to_bf16(float f) {
    unsigned int u = __builtin_bit_cast(unsigned int, f);
    u = (u + 0x7FFFu + ((u >> 16) & 1u)) >> 16;
    return (unsigned short)u;
}
__device__ __forceinline__ float bf16_to_f32(unsigned short h) {
    unsigned int u = ((unsigned int)h) << 16;
    return __builtin_bit_cast(float, u);
}
__device__ __forceinline__ void gload_lds16(const void* gsrc, void* lds) {
    __builtin_amdgcn_global_load_lds(
        (const __attribute__((address_space(1))) unsigned int*)gsrc,
        (__attribute__((address_space(3))) unsigned int*)lds,
        16, 0, 0);
}

// WtT linear image per [g][ks]: granule s in [0,1024), s>>2 = n-row, s&3 = p.
// Contents: source granule (p ^ ((n>>1)&3)) of Wt[n][ks*32 .. +31] so that a
// LINEAR global_load_lds write produces the swizzled LDS tile read with
// byte ^= ((n>>1)&3)<<4.
__global__ __launch_bounds__(256) void convert_w1(const float* __restrict__ W1,
                                                  unsigned short* __restrict__ WtT) {
    int t = blockIdx.x * blockDim.x + threadIdx.x;
    if (t >= 2 * NK * BN * BK) return;
    int g  = t / (NK * BN * BK);
    int r  = t % (NK * BN * BK);
    int ks = r / (BN * BK);
    int r2 = r % (BN * BK);   // linear element within tile
    int s  = r2 >> 3;         // 16B granule
    int j  = r2 & 7;
    int n  = s >> 2;
    int p  = s & 3;
    int k  = ks * BK + ((p ^ ((n >> 1) & 3)) << 3) + j;
    WtT[t] = f32_to_bf16(W1[(size_t)(g * IN_DIM + k) * HIDDEN + n]);
}

// P = bf16(X) @ bf16(W1half). BM=128, BN=256, BK=32, 24 K-steps.
// All staging via global_load_lds (A as f32, B pre-swizzled bf16), double
// buffered, counted vmcnt(4) so loads stay in flight across raw barriers.
__global__ __launch_bounds__(512, 4) void node_gemm(const float* __restrict__ X0,
                                                    const float* __restrict__ X1,
                                                    const unsigned short* __restrict__ WtT,
                                                    unsigned short* __restrict__ Pout,
                                                    unsigned short* __restrict__ Qout) {
    const int g = blockIdx.y;
    const float* __restrict__ X = g ? X1 : X0;
    unsigned short* __restrict__ Out = g ? Qout : Pout;
    const char* wt_base = (const char*)WtT + (size_t)g * NK * WT_TILE_BYTES;

    // A: [2][128 rows][8 granules x16B] f32, swizzle p^(r&7)   (16KB each)
    // B: [2][256 rows][4 granules x16B] bf16, swizzle p^((n>>1)&3) (16KB each)
    __shared__ __attribute__((aligned(16))) char As[2][BM * BK * 4];
    __shared__ __attribute__((aligned(16))) char Bs[2][BN * BK * 2];

    const int m0   = blockIdx.x * BM;
    const int tid  = threadIdx.x;
    const int lane = tid & 63;
    const int wid  = tid >> 6;
    const int wm   = wid >> 2; // 0..1 -> 64-row slab
    const int wn   = wid & 3;  // 0..3 -> 64-col slab

    f32x4 acc[4][4] = {};

    // per-lane invariant pieces of the A source address
    const int a_row_in_inst = lane >> 3;                 // 0..7
    const int a_perm        = ((lane & 7) ^ a_row_in_inst) << 2; // f32 offset in k-slab

    auto issue = [&](int ks, int buf) {
        const int k0 = ks * BK;
        // A: 2 insts/wave, 8 rows each
#pragma unroll
        for (int j = 0; j < 2; ++j) {
            int r  = (wid * 2 + j) * 8 + a_row_in_inst;  // 0..127
            int rg = m0 + r;
            if (rg >= N_NODES) rg = N_NODES - 1;         // pad rows get copies
            gload_lds16(X + (size_t)rg * IN_DIM + k0 + a_perm,
                        As[buf] + (wid * 2 + j) * 1024);
        }
        // B: 2 insts/wave, linear pre-swizzled source
        const char* src = wt_base + (size_t)ks * WT_TILE_BYTES + (wid * 2) * 1024 + lane * 16;
#pragma unroll
        for (int j = 0; j < 2; ++j)
            gload_lds16(src + j * 1024, Bs[buf] + (wid * 2 + j) * 1024);
    };

    auto compute = [&](int buf) {
        const char* ab = As[buf];
        const char* bb = Bs[buf];
        const int lr = lane & 15;
        const int c  = lane >> 4;   // k-chunk: f32 granules 2c,2c+1 / bf16 granule c
        short8 bfr[4];
#pragma unroll
        for (int ni = 0; ni < 4; ++ni) {
            int n = wn * 64 + ni * 16 + lr;
            bfr[ni] = *(const short8*)(bb + n * 64 + ((c ^ ((n >> 1) & 3)) << 4));
        }
        __builtin_amdgcn_s_setprio(1);
#pragma unroll
        for (int mi = 0; mi < 4; ++mi) {
            int r = wm * 64 + mi * 16 + lr;
            const char* rowp = ab + r * 128;
            float4 lo = *(const float4*)(rowp + (((2 * c)     ^ (r & 7)) << 4));
            float4 hi = *(const float4*)(rowp + (((2 * c + 1) ^ (r & 7)) << 4));
            short8 a;
            a[0] = f32_to_bf16(lo.x); a[1] = f32_to_bf16(lo.y);
            a[2] = f32_to_bf16(lo.z); a[3] = f32_to_bf16(lo.w);
            a[4] = f32_to_bf16(hi.x); a[5] = f32_to_bf16(hi.y);
            a[6] = f32_to_bf16(hi.z); a[7] = f32_to_bf16(hi.w);
#pragma unroll
            for (int ni = 0; ni < 4; ++ni)
                // swapped operands: D[n][m] -> lane holds 4 consecutive n-cols
                acc[mi][ni] = __builtin_amdgcn_mfma_f32_16x16x32_bf16(
                    bfr[ni], a, acc[mi][ni], 0, 0, 0);
        }
        __builtin_amdgcn_s_setprio(0);
    };

    // prologue: tiles 0 and 1 in flight
    issue(0, 0);
    issue(1, 1);
    WAITV(4);                       // tile 0 landed (mine)
    __builtin_amdgcn_s_barrier();   // everyone's tile 0 landed
    FENCE();

    for (int ks = 0; ks < NK; ++ks) {
        const int buf = ks & 1;
        compute(buf);
        FENCE();
        __builtin_amdgcn_s_barrier();   // all waves done reading buf
        FENCE();
        if (ks + 2 < NK) {
            issue(ks + 2, buf);         // overwrite just-read buffer
            WAITV(4);                   // tile ks+1 landed (4 newest still in flight)
        } else {
            WAITV(0);                   // tail: drain
        }
        __builtin_amdgcn_s_barrier();   // everyone's tile ks+1 landed
        FENCE();
    }

    // store: m = m0 + wm*64 + mi*16 + (lane&15), n = wn*64 + ni*16 + (lane>>4)*4 + reg
    const int mrow = wm * 64 + (lane & 15);
    const int nb0  = wn * 64 + ((lane >> 4) << 2);
#pragma unroll
    for (int mi = 0; mi < 4; ++mi) {
        size_t mg = (size_t)(m0 + mrow + mi * 16);
#pragma unroll
        for (int ni = 0; ni < 4; ++ni) {
            f32x4 a = acc[mi][ni];
            ushort4 w;
            w.x = f32_to_bf16(a[0]); w.y = f32_to_bf16(a[1]);
            w.z = f32_to_bf16(a[2]); w.w = f32_to_bf16(a[3]);
            *(ushort4*)(Out + mg * HIDDEN + nb0 + ni * 16) = w;
        }
    }
}

// out[e] = relu(P[s]+Q[d]+b1) . W2 + b2 ; one wave per edge, lane j owns dims 4j..4j+3
__global__ __launch_bounds__(256) void edge_mlp(const unsigned short* __restrict__ P,
                                                const unsigned short* __restrict__ Q,
                                                const int* __restrict__ s_idx,
                                                const int* __restrict__ d_idx,
                                                const float* __restrict__ b1,
                                                const float* __restrict__ W2,
                                                const float* __restrict__ b2,
                                                float* __restrict__ out) {
    const int lane = threadIdx.x & 63;
    const int gw = (blockIdx.x * blockDim.x + threadIdx.x) >> 6;
    const int nw = (gridDim.x * blockDim.x) >> 6;
    const float4 b1v = *(const float4*)(b1 + lane * 4);
    const float4 w2v = *(const float4*)(W2 + lane * 4);
    const float b2s = *b2;
    for (int e = gw; e < N_EDGES; e += nw) {
        int s = s_idx[e];
        int d = d_idx[e];
        ushort4 pv = *(const ushort4*)(P + (size_t)s * HIDDEN + lane * 4);
        ushort4 qv = *(const ushort4*)(Q + (size_t)d * HIDDEN + lane * 4);
        float h, sum;
        h = bf16_to_f32(pv.x) + bf16_to_f32(qv.x) + b1v.x; h = fmaxf(h, 0.f); sum  = h * w2v.x;
        h = bf16_to_f32(pv.y) + bf16_to_f32(qv.y) + b1v.y; h = fmaxf(h, 0.f); sum += h * w2v.y;
        h = bf16_to_f32(pv.z) + bf16_to_f32(qv.z) + b1v.z; h = fmaxf(h, 0.f); sum += h * w2v.z;
        h = bf16_to_f32(pv.w) + bf16_to_f32(qv.w) + b1v.w; h = fmaxf(h, 0.f); sum += h * w2v.w;
#pragma unroll
        for (int off = 32; off; off >>= 1) sum += __shfl_xor(sum, off, 64);
        if (lane == 0) out[e] = sum + b2s;
    }
}

extern "C" void kernel_launch(void* const* d_in, const int* in_sizes, int n_in,
                              void* d_out, int out_size, void* d_ws, size_t ws_size,
                              hipStream_t stream) {
    const float* x_src = (const float*)d_in[0];
    const float* x_dst = (const float*)d_in[1];
    const int*   s_idx = (const int*)d_in[2];
    const int*   d_idx = (const int*)d_in[3];
    const float* W1    = (const float*)d_in[4];
    const float* b1    = (const float*)d_in[5];
    const float* W2    = (const float*)d_in[6];
    const float* b2    = (const float*)d_in[7];
    float* out = (float*)d_out;

    char* ws = (char*)d_ws;
    // layout: WtT (786432 B) | P (M_PAD*256*2 B) | Q (M_PAD*256*2 B) => ~103.3 MB
    unsigned short* WtT = (unsigned short*)ws;
    unsigned short* P   = (unsigned short*)(ws + 786432);
    unsigned short* Q   = (unsigned short*)(ws + 786432 + (size_t)M_PAD * HIDDEN * 2);

    convert_w1<<<(2 * NK * BN * BK + 255) / 256, 256, 0, stream>>>(W1, WtT);

    dim3 gg(M_BLOCKS, 2);
    node_gemm<<<gg, 512, 0, stream>>>(x_src, x_dst, WtT, P, Q);

    edge_mlp<<<2048, 256, 0, stream>>>(P, Q, s_idx, d_idx, b1, W2, b2, out);
}

// Round 5
// 239.311 us; speedup vs baseline: 1.1191x; 1.0508x over previous
//
#include <hip/hip_runtime.h>
#include <hip/hip_bf16.h>

#define N_NODES 100000
#define N_EDGES 262144
#define IN_DIM 768
#define HIDDEN 256
#define BM 128
#define BN 256
#define BK 32
#define NK (IN_DIM / BK)      // 24
#define M_BLOCKS 782          // ceil(100000/128)
#define M_PAD (M_BLOCKS * BM) // 100096
#define WT_TILE_BYTES (BN * BK * 2) // 16384

typedef __attribute__((ext_vector_type(8))) short short8;
typedef __attribute__((ext_vector_type(4))) float f32x4;

#define WAITV(n) asm volatile("s_waitcnt vmcnt(" #n ")" ::: "memory")
#define WAITL()  asm volatile("s_waitcnt lgkmcnt(0)" ::: "memory")
#define FENCE()  asm volatile("" ::: "memory")

__device__ __forceinline__ unsigned short f32_to_bf16(float f) {
    unsigned int u = __builtin_bit_cast(unsigned int, f);
    u = (u + 0x7FFFu + ((u >> 16) & 1u)) >> 16;
    return (unsigned short)u;
}
__device__ __forceinline__ float bf16_to_f32(unsigned short h) {
    unsigned int u = ((unsigned int)h) << 16;
    return __builtin_bit_cast(float, u);
}
__device__ __forceinline__ void gload_lds16(const void* gsrc, void* lds) {
    __builtin_amdgcn_global_load_lds(
        (const __attribute__((address_space(1))) unsigned int*)gsrc,
        (__attribute__((address_space(3))) unsigned int*)lds,
        16, 0, 0);
}

// WtT linear image per [g][ks]: granule s in [0,1024), n = s>>2, p = s&3.
// Content = logical granule (p ^ ((n>>1)&3)) of Wt[n][ks*32..+31], so a LINEAR
// global_load_lds write yields the LDS tile read with granule ^= (n>>1)&3.
__global__ __launch_bounds__(256) void convert_w1(const float* __restrict__ W1,
                                                  unsigned short* __restrict__ WtT) {
    int t = blockIdx.x * blockDim.x + threadIdx.x;
    if (t >= 2 * NK * BN * BK) return;
    int g  = t / (NK * BN * BK);
    int r  = t % (NK * BN * BK);
    int ks = r / (BN * BK);
    int r2 = r % (BN * BK);
    int s  = r2 >> 3;
    int j  = r2 & 7;
    int n  = s >> 2;
    int p  = s & 3;
    int k  = ks * BK + ((p ^ ((n >> 1) & 3)) << 3) + j;
    WtT[t] = f32_to_bf16(W1[(size_t)(g * IN_DIM + k) * HIDDEN + n]);
}

// P = bf16(X) @ bf16(W1half). BM=128, BN=256, BK=32, NK=24.
// 3-deep LDS rings (A 3x8KB, B 3x16KB), ONE s_barrier + ONE counted WAITV(4)
// per K-step. A: reg bank (2-step prefetch) -> convert once -> ds_write.
// B: pre-swizzled global_load_lds (L2-resident weights).
__global__ __launch_bounds__(512, 4) void node_gemm(const float* __restrict__ X0,
                                                    const float* __restrict__ X1,
                                                    const unsigned short* __restrict__ WtT,
                                                    unsigned short* __restrict__ Pout,
                                                    unsigned short* __restrict__ Qout) {
    const int g = blockIdx.y;
    const float* __restrict__ X = g ? X1 : X0;
    unsigned short* __restrict__ Out = g ? Qout : Pout;
    const char* wt_base = (const char*)WtT + (size_t)g * NK * WT_TILE_BYTES;

    __shared__ __attribute__((aligned(16))) char As[3][BM * BK * 2]; // 3 x 8KB
    __shared__ __attribute__((aligned(16))) char Bs[3][BN * BK * 2]; // 3 x 16KB

    const int m0   = blockIdx.x * BM;
    const int tid  = threadIdx.x;
    const int lane = tid & 63;
    const int wid  = tid >> 6;
    const int wm   = wid >> 2; // 0..1 -> 64-row slab
    const int wn   = wid & 3;  // 0..3 -> 64-col slab

    // staging coords: thread -> (row sr, granule sc) ; granule = 8 f32 = 32B
    const int sr = tid >> 2;   // 0..127
    const int sc = tid & 3;    // 0..3
    int srow_g = m0 + sr;
    if (srow_g >= N_NODES) srow_g = N_NODES - 1;   // pad rows get copies
    const float* aptr = X + (size_t)srow_g * IN_DIM + sc * 8;
    // A LDS write offset (swizzled)
    const int awoff = sr * 64 + (((sc ^ ((sr >> 1) & 3))) << 4);

    f32x4 acc[4][4] = {};
    float4 bank0[2], bank1[2];

    auto a_issue = [&](int ks, float4 (&bk)[2]) {
        const float* p = aptr + ks * BK;
        bk[0] = *(const float4*)(p);
        bk[1] = *(const float4*)(p + 4);
    };
    auto a_write = [&](int slot, const float4 (&bk)[2]) {
        short8 w;
        w[0] = (short)f32_to_bf16(bk[0].x); w[1] = (short)f32_to_bf16(bk[0].y);
        w[2] = (short)f32_to_bf16(bk[0].z); w[3] = (short)f32_to_bf16(bk[0].w);
        w[4] = (short)f32_to_bf16(bk[1].x); w[5] = (short)f32_to_bf16(bk[1].y);
        w[6] = (short)f32_to_bf16(bk[1].z); w[7] = (short)f32_to_bf16(bk[1].w);
        *(short8*)(As[slot] + awoff) = w;
    };
    auto b_issue = [&](int ks, int slot) {
        const char* src = wt_base + (size_t)ks * WT_TILE_BYTES + wid * 2048 + lane * 16;
        char* dst = Bs[slot] + wid * 2048;  // wave-uniform; HW adds lane*16
        gload_lds16(src, dst);
        gload_lds16(src + 1024, dst + 1024);
    };

    const int lr = lane & 15;
    const int c  = lane >> 4;

    auto step = [&](int ks, float4 (&bk)[2]) {
        const char* Ab = As[ks % 3];
        const char* Bb = Bs[ks % 3];
        short8 afr[4], bfr[4];
#pragma unroll
        for (int mi = 0; mi < 4; ++mi) {
            int r = wm * 64 + mi * 16 + lr;
            afr[mi] = *(const short8*)(Ab + r * 64 + ((c ^ ((r >> 1) & 3)) << 4));
        }
#pragma unroll
        for (int ni = 0; ni < 4; ++ni) {
            int n = wn * 64 + ni * 16 + lr;
            bfr[ni] = *(const short8*)(Bb + n * 64 + ((c ^ ((n >> 1) & 3)) << 4));
        }
        __builtin_amdgcn_s_setprio(1);
#pragma unroll
        for (int mi = 0; mi < 4; ++mi)
#pragma unroll
            for (int ni = 0; ni < 4; ++ni)
                // swapped operands: D[n][m] -> lane holds 4 consecutive n-cols
                acc[mi][ni] = __builtin_amdgcn_mfma_f32_16x16x32_bf16(
                    bfr[ni], afr[mi], acc[mi][ni], 0, 0, 0);
        __builtin_amdgcn_s_setprio(0);
        // prefetch B(ks+2) into its ring slot (last read at step ks-1)
        const int wslot = (ks + 2) % 3;
        const int kB = (ks + 2 < NK) ? ks + 2 : NK - 1;
        b_issue(kB, wslot);
        WAITV(4);              // drains A(ks+2) regs + B(ks+1) gloads
        a_write(wslot, bk);    // convert once, one ds_write_b128
        const int kA = (ks + 4 < NK) ? ks + 4 : NK - 1;
        a_issue(kA, bk);       // refill bank, consumed at step ks+2
        FENCE();
        __builtin_amdgcn_s_barrier();
        FENCE();
    };

    // ---- prologue: fill A slots 0,1 / B slots 0,1 / banks A(2),A(3)
    a_issue(0, bank0);
    a_issue(1, bank1);
    b_issue(0, 0);
    WAITV(4);                  // A(0) landed
    a_write(0, bank0);
    a_issue(2, bank0);
    WAITV(4);                  // A(1) landed
    a_write(1, bank1);
    b_issue(1, 1);
    a_issue(3, bank1);
    WAITV(6);                  // B(0) landed
    WAITL();                   // my ds_writes done
    FENCE();
    __builtin_amdgcn_s_barrier();
    FENCE();

    // ---- main loop, unrolled x2 for static bank selection (NK even)
    for (int ks2 = 0; ks2 < NK; ks2 += 2) {
        step(ks2, bank0);
        step(ks2 + 1, bank1);
    }

    // store: m = m0 + wm*64 + mi*16 + (lane&15), n = wn*64 + ni*16 + (lane>>4)*4 + reg
    const int mrow = wm * 64 + lr;
    const int nb0  = wn * 64 + (c << 2);
#pragma unroll
    for (int mi = 0; mi < 4; ++mi) {
        size_t mg = (size_t)(m0 + mrow + mi * 16);
#pragma unroll
        for (int ni = 0; ni < 4; ++ni) {
            f32x4 a = acc[mi][ni];
            ushort4 w;
            w.x = f32_to_bf16(a[0]); w.y = f32_to_bf16(a[1]);
            w.z = f32_to_bf16(a[2]); w.w = f32_to_bf16(a[3]);
            *(ushort4*)(Out + mg * HIDDEN + nb0 + ni * 16) = w;
        }
    }
    WAITV(0);                  // drain tail gload_lds before LDS is reallocated
}

// out[e] = relu(P[s]+Q[d]+b1) . W2 + b2 ; one wave per edge, lane j owns dims 4j..4j+3
__global__ __launch_bounds__(256) void edge_mlp(const unsigned short* __restrict__ P,
                                                const unsigned short* __restrict__ Q,
                                                const int* __restrict__ s_idx,
                                                const int* __restrict__ d_idx,
                                                const float* __restrict__ b1,
                                                const float* __restrict__ W2,
                                                const float* __restrict__ b2,
                                                float* __restrict__ out) {
    const int lane = threadIdx.x & 63;
    const int gw = (blockIdx.x * blockDim.x + threadIdx.x) >> 6;
    const int nw = (gridDim.x * blockDim.x) >> 6;
    const float4 b1v = *(const float4*)(b1 + lane * 4);
    const float4 w2v = *(const float4*)(W2 + lane * 4);
    const float b2s = *b2;
    for (int e = gw; e < N_EDGES; e += nw) {
        int s = s_idx[e];
        int d = d_idx[e];
        ushort4 pv = *(const ushort4*)(P + (size_t)s * HIDDEN + lane * 4);
        ushort4 qv = *(const ushort4*)(Q + (size_t)d * HIDDEN + lane * 4);
        float h, sum;
        h = bf16_to_f32(pv.x) + bf16_to_f32(qv.x) + b1v.x; h = fmaxf(h, 0.f); sum  = h * w2v.x;
        h = bf16_to_f32(pv.y) + bf16_to_f32(qv.y) + b1v.y; h = fmaxf(h, 0.f); sum += h * w2v.y;
        h = bf16_to_f32(pv.z) + bf16_to_f32(qv.z) + b1v.z; h = fmaxf(h, 0.f); sum += h * w2v.z;
        h = bf16_to_f32(pv.w) + bf16_to_f32(qv.w) + b1v.w; h = fmaxf(h, 0.f); sum += h * w2v.w;
#pragma unroll
        for (int off = 32; off; off >>= 1) sum += __shfl_xor(sum, off, 64);
        if (lane == 0) out[e] = sum + b2s;
    }
}

extern "C" void kernel_launch(void* const* d_in, const int* in_sizes, int n_in,
                              void* d_out, int out_size, void* d_ws, size_t ws_size,
                              hipStream_t stream) {
    const float* x_src = (const float*)d_in[0];
    const float* x_dst = (const float*)d_in[1];
    const int*   s_idx = (const int*)d_in[2];
    const int*   d_idx = (const int*)d_in[3];
    const float* W1    = (const float*)d_in[4];
    const float* b1    = (const float*)d_in[5];
    const float* W2    = (const float*)d_in[6];
    const float* b2    = (const float*)d_in[7];
    float* out = (float*)d_out;

    char* ws = (char*)d_ws;
    // layout: WtT (786432 B) | P (M_PAD*256*2 B) | Q (M_PAD*256*2 B) => ~103.3 MB
    unsigned short* WtT = (unsigned short*)ws;
    unsigned short* P   = (unsigned short*)(ws + 786432);
    unsigned short* Q   = (unsigned short*)(ws + 786432 + (size_t)M_PAD * HIDDEN * 2);

    convert_w1<<<(2 * NK * BN * BK + 255) / 256, 256, 0, stream>>>(W1, WtT);

    dim3 gg(M_BLOCKS, 2);
    node_gemm<<<gg, 512, 0, stream>>>(x_src, x_dst, WtT, P, Q);

    edge_mlp<<<2048, 256, 0, stream>>>(P, Q, s_idx, d_idx, b1, W2, b2, out);
}